// Round 2
// baseline (448.377 us; speedup 1.0000x reference)
//
#include <hip/hip_runtime.h>
#include <math.h>

#define NN 100000
#define EE 1600000
#define GG 256
#define HH 128
#define BSH 8                 /* 256 nodes per bucket */
#define NBK 391               /* ceil(NN/256) */
#define PASSA_WG 391          /* r10-proven: 16 edges/thread */
#define CAPB 6144             /* per-bucket region: edges(~4092) + self/pad8(<=2048) */

typedef __attribute__((ext_vector_type(8))) short short8;   // 8 bf16 (4 VGPRs)
typedef __attribute__((ext_vector_type(4))) float f32x4;    // MFMA acc
typedef __attribute__((ext_vector_type(2))) float f32x2;    // packed f32 pair

union U4S8 { uint4 u; short8 s; };

// ---------------------------------------------------------------------------
// bf16 helpers (RNE pack, cheap unpack)
// ---------------------------------------------------------------------------
static __device__ __forceinline__ unsigned bf16rne(float f) {
    const unsigned u = __float_as_uint(f);
    return (u + 0x7fffu + ((u >> 16) & 1u)) >> 16;
}
static __device__ __forceinline__ unsigned packbf(float a, float b) {
    return bf16rne(a) | (bf16rne(b) << 16);
}
static __device__ __forceinline__ float bflo(unsigned u) { return __uint_as_float(u << 16); }
static __device__ __forceinline__ float bfhi(unsigned u) { return __uint_as_float(u & 0xffff0000u); }
static __device__ __forceinline__ f32x2 up2(unsigned u) {
    f32x2 r; r.x = bflo(u); r.y = bfhi(u); return r;
}

// ---------------------------------------------------------------------------
// Fused setup: wprep (ids 0..24575), bnprep (..24703), cursinit (..25094),
// psum zero (..57862), gcnt zero (..58118), dtype detect (id 58119).
// ---------------------------------------------------------------------------
__global__ __launch_bounds__(256) void setup_k(
    const int* __restrict__ ei, const int* __restrict__ batch,
    const float* __restrict__ w1, const float* __restrict__ w2,
    const float* __restrict__ w3,
    const float* __restrict__ b1, const float* __restrict__ g1,
    const float* __restrict__ be1, const float* __restrict__ m1,
    const float* __restrict__ v1,
    const float* __restrict__ b2, const float* __restrict__ g2,
    const float* __restrict__ be2, const float* __restrict__ m2,
    const float* __restrict__ v2,
    const float* __restrict__ b3, const float* __restrict__ g3,
    const float* __restrict__ be3, const float* __restrict__ m3,
    const float* __restrict__ v3,
    unsigned* __restrict__ bt, float* __restrict__ sc, float* __restrict__ sh,
    int* __restrict__ cursor, float* __restrict__ psum, int* __restrict__ gcnt,
    int* __restrict__ flags) {
    const int id = blockIdx.x * 256 + threadIdx.x;
    if (id < 24576) {
        const int w = id >> 13;
        const int rem = id & 8191;
        const int n = rem >> 6;
        const int kk = rem & 63;                      // k-pair
        const float* W = (w == 0) ? w1 : (w == 1) ? w2 : w3;
        bt[id] = packbf(W[(2 * kk) * HH + n], W[(2 * kk + 1) * HH + n]);
    } else if (id < 24704) {
        const int c = id - 24576;
        float s;
        s = g1[c] / sqrtf(v1[c] + 1e-5f);
        sc[c] = s;           sh[c] = (b1[c] - m1[c]) * s + be1[c];
        s = g2[c] / sqrtf(v2[c] + 1e-5f);
        sc[128 + c] = s;     sh[128 + c] = (b2[c] - m2[c]) * s + be2[c];
        s = g3[c] / sqrtf(v3[c] + 1e-5f);
        sc[256 + c] = s;     sh[256 + c] = (b3[c] - m3[c]) * s + be3[c];
    } else if (id < 25095) {
        const int b = id - 24704;
        cursor[b] = b * CAPB;
    } else if (id < 57863) {
        psum[id - 25095] = 0.0f;
    } else if (id < 58119) {
        gcnt[id - 57863] = 0;
    } else if (id == 58119) {
        int e64 = 1;
        for (int j = 0; j < 8; ++j) {
            if (ei[2 * EE - 1 - 2 * j] != 0) { e64 = 0; break; }
        }
        flags[0] = e64;
        flags[1] = (batch[NN - 1] == 0) ? 1 : 0;
    }
}
#define SETUP_GRID 228   /* ceil(58120/256) */

// ---------------------------------------------------------------------------
// pass A (r10 config): 391 wgs x 4096 edges (16/thread).
// ---------------------------------------------------------------------------
__global__ __launch_bounds__(256) void passA_k(const int* __restrict__ ei,
                                               const int* __restrict__ flags,
                                               int* __restrict__ cursor,
                                               unsigned* __restrict__ pairs) {
    __shared__ int h[NBK];
    __shared__ int rbase[NBK];
    const int tid = threadIdx.x;
    for (int i = tid; i < NBK; i += 256) h[i] = 0;
    __syncthreads();
    const bool e64 = flags[0] != 0;
    const int base = blockIdx.x * 4096;
    int scache[16], dcache[16];
#pragma unroll
    for (int j = 0; j < 16; ++j) {
        const int e = base + j * 256 + tid;
        int s = -1, d = 0;
        if (e < EE) {
            s = e64 ? ei[2 * e] : ei[e];
            d = e64 ? ei[2 * (EE + e)] : ei[EE + e];
            atomicAdd(&h[d >> BSH], 1);
        }
        scache[j] = s; dcache[j] = d;
    }
    __syncthreads();
    for (int i = tid; i < NBK; i += 256) {
        const int c = h[i];
        rbase[i] = c ? atomicAdd(&cursor[i], c) : 0;
    }
    __syncthreads();
    for (int i = tid; i < NBK; i += 256) h[i] = 0;
    __syncthreads();
#pragma unroll
    for (int j = 0; j < 16; ++j) {
        const int s = scache[j];
        if (s >= 0) {
            const int d = dcache[j];
            const int b = d >> BSH;
            const int r = atomicAdd(&h[b], 1);
            pairs[rbase[b] + r] = ((unsigned)(d & 255) << 17) | (unsigned)s;
        }
    }
}

// ---------------------------------------------------------------------------
// pass B: one wg per bucket -> offs/degcnt/dinv + bucketed CSR with
// self-inclusive padding to a multiple of 8 (sentinel NN = zero row).
// NEW (r13): per-node adjacency lists are insertion-sorted by src id in an
// LDS image before writing out. Gathers then sweep the 25.6MB table
// monotonically -> quasi-streaming L3/HBM reads instead of random 64B.
// ---------------------------------------------------------------------------
__global__ __launch_bounds__(256) void passB_k(const unsigned* __restrict__ pairs,
                                               const int* __restrict__ cursor,
                                               int* __restrict__ offs,
                                               int* __restrict__ degcnt,
                                               float* __restrict__ dinv,
                                               int* __restrict__ csr) {
    __shared__ unsigned pk[CAPB];
    __shared__ int lcs[CAPB];
    __shared__ int cnt[256];
    __shared__ int loff[256];
    __shared__ int sc[256];
    __shared__ int tot;
    const int tid = threadIdx.x;
    const int b = blockIdx.x;
    const int p0 = b * CAPB;
    const int np = cursor[b] - p0;           // real edges in bucket
    const int nb0 = b << BSH;
    const int nnode = (NN - nb0 < 256) ? (NN - nb0) : 256;

    cnt[tid] = 0;
    __syncthreads();
    for (int i = tid; i < np; i += 256) {
        const unsigned p = pairs[p0 + i];
        pk[i] = p;
        atomicAdd(&cnt[p >> 17], 1);
    }
    __syncthreads();
    const int creal = cnt[tid];
    const int cpad = (tid < nnode) ? ((creal + 8) & ~7) : 0;   // +self, pad to 8
    sc[tid] = cpad;
    __syncthreads();
    for (int off = 1; off < 256; off <<= 1) {
        int t = (tid >= off) ? sc[tid - off] : 0;
        __syncthreads();
        sc[tid] += t;
        __syncthreads();
    }
    const int ex = sc[tid] - cpad;
    loff[tid] = ex;
    if (tid == 255) tot = sc[255];
    if (tid < nnode) {
        const int node = nb0 + tid;
        offs[node] = p0 + ex;
        degcnt[node] = creal;
        dinv[node] = 1.0f / sqrtf((float)(creal + 1));
    }
    __syncthreads();
    cnt[tid] = 0;
    __syncthreads();
    for (int i = tid; i < np; i += 256) {
        const unsigned p = pk[i];
        const int dl = (int)(p >> 17);
        const int r = atomicAdd(&cnt[dl], 1);
        lcs[loff[dl] + r] = (int)(p & 0x1FFFFu);
    }
    __syncthreads();
    if (tid < nnode) {
        const int b0 = loff[tid];
        // insertion sort by src (lists avg ~17, max ~45) for sweep locality
        for (int j = 1; j < creal; ++j) {
            const int key = lcs[b0 + j];
            int k2 = j - 1;
            while (k2 >= 0 && lcs[b0 + k2] > key) {
                lcs[b0 + k2 + 1] = lcs[b0 + k2];
                --k2;
            }
            lcs[b0 + k2 + 1] = key;
        }
        lcs[b0 + creal] = nb0 + tid;                       // self loop
        for (int j = creal + 1; j < cpad; ++j) lcs[b0 + j] = NN;   // pad
    }
    __syncthreads();
    for (int i = tid; i < tot; i += 256) csr[p0 + i] = lcs[i];   // coalesced out
}

// ---------------------------------------------------------------------------
// Hybrid MFMA bf16 GEMM (LDS-staged B^T + direct C^T stores), verified r10.
// Used only for layer 1 (f32 input x). Row M sentinel zeroed; dinv fused.
// ---------------------------------------------------------------------------
static __device__ __forceinline__ float sani(float v) {
    if (isnan(v)) return 0.0f;
    if (isinf(v)) return v > 0.0f ? 1e6f : -1e6f;
    return v;
}

__global__ __launch_bounds__(256) void gemm_mfma_k(const float* __restrict__ Af,
                                                   const unsigned* __restrict__ btg,
                                                   const float* __restrict__ dinv,
                                                   unsigned* __restrict__ C, int M) {
    __shared__ unsigned lds_u[8704];   // B^T: 128 rows x 68 uints (34816 B)
    const int tid = threadIdx.x;
    const int wave = tid >> 6;
    const int lane = tid & 63;
    const int nl = lane & 15;
    const int q = lane >> 4;
    const int row0 = blockIdx.x * 64 + wave * 16;
    const int rowg = row0 + nl;
    const int rowa = min(rowg, M - 1);

    {
        const uint4* __restrict__ bg4 = (const uint4*)btg;
        for (int i = tid; i < 2048; i += 256) {
            const int n = i >> 4, w4 = i & 15;
            *(uint4*)&lds_u[n * 68 + w4 * 4] = bg4[n * 16 + w4];
        }
    }

    short8 a[4];
#pragma unroll
    for (int ks = 0; ks < 4; ++ks) {
        const float4 p = *(const float4*)(Af + (size_t)rowa * HH + ks * 32 + q * 8);
        const float4 r = *(const float4*)(Af + (size_t)rowa * HH + ks * 32 + q * 8 + 4);
        U4S8 cv;
        cv.u = make_uint4(packbf(sani(p.x), sani(p.y)), packbf(sani(p.z), sani(p.w)),
                          packbf(sani(r.x), sani(r.y)), packbf(sani(r.z), sani(r.w)));
        a[ks] = cv.s;
    }

    __syncthreads();   // B^T staged

    f32x4 acc[8];
#pragma unroll
    for (int t = 0; t < 8; ++t) acc[t] = (f32x4)0.0f;

    const unsigned short* __restrict__ bts = (const unsigned short*)lds_u;
#pragma unroll
    for (int ks = 0; ks < 4; ++ks) {
#pragma unroll
        for (int t = 0; t < 8; ++t) {
            const int n = t * 16 + nl;
            const short8 b = *(const short8*)(bts + n * 136 + ks * 32 + q * 8);
            acc[t] = __builtin_amdgcn_mfma_f32_16x16x32_bf16(b, a[ks], acc[t], 0, 0, 0);
        }
    }

    if (rowg < M) {
        const float dsc = dinv[rowg];
        unsigned* crow = C + (size_t)rowg * 64;
#pragma unroll
        for (int t = 0; t < 8; ++t) {
            uint2 o;
            o.x = packbf(dsc * acc[t][0], dsc * acc[t][1]);
            o.y = packbf(dsc * acc[t][2], dsc * acc[t][3]);
            *(uint2*)(crow + t * 8 + q * 2) = o;
        }
    } else if (rowg == M) {
        unsigned* crow = C + (size_t)M * 64;
#pragma unroll
        for (int t = 0; t < 8; ++t)
            *(uint2*)(crow + t * 8 + q * 2) = make_uint2(0u, 0u);
    }
}

// ---------------------------------------------------------------------------
// Interleaved 4-node gather (r12) + packed f32x2 accumulation (r13):
// 8 independent 16B gathers in flight + 8 csr prefetches per iteration;
// reduction uses v_pk_add_f32 via f32x2 (25% fewer inner-loop VALU ops).
// Nodes past their npad read the zeroed sentinel row NN.
// ---------------------------------------------------------------------------
static __device__ __forceinline__ void gather4(
    const char* __restrict__ hb, const int* __restrict__ csr,
    const int st[4], const int np[4], const int maxp,
    const int sub, const unsigned cgo, f32x2 acc[4][4]) {
    int ia[4], ib[4];
#pragma unroll
    for (int i = 0; i < 4; ++i) {
        ia[i] = csr[st[i] + sub];
        ib[i] = csr[st[i] + 4 + sub];
    }
    for (int e = 0; e < maxp; e += 8) {
        uint4 r[8];
#pragma unroll
        for (int i = 0; i < 4; ++i) {
            const bool act = (e < np[i]);                 // wave-uniform
            const unsigned sA = act ? (unsigned)ia[i] : (unsigned)NN;
            const unsigned sB = act ? (unsigned)ib[i] : (unsigned)NN;
            r[2 * i]     = *(const uint4*)(hb + ((sA << 8) | cgo));
            r[2 * i + 1] = *(const uint4*)(hb + ((sB << 8) | cgo));
        }
#pragma unroll
        for (int i = 0; i < 4; ++i) {                     // prefetch next iter
            ia[i] = csr[st[i] + e + 8 + sub];
            ib[i] = csr[st[i] + e + 12 + sub];
        }
#pragma unroll
        for (int i = 0; i < 4; ++i) {
            const uint4 rA = r[2 * i];
            const uint4 rB = r[2 * i + 1];
            acc[i][0] += up2(rA.x) + up2(rB.x);
            acc[i][1] += up2(rA.y) + up2(rB.y);
            acc[i][2] += up2(rA.z) + up2(rB.z);
            acc[i][3] += up2(rA.w) + up2(rB.w);
        }
    }
}

// ---------------------------------------------------------------------------
// FUSED aggregate(L) + gemm(L+1): block = 4 waves x 4 nodes/wave = 16 nodes.
// ---------------------------------------------------------------------------
__global__ __launch_bounds__(256) void agg_gemm_k(
    const unsigned* __restrict__ hin, const int* __restrict__ csr,
    const int* __restrict__ offs, const int* __restrict__ cnt,
    const float* __restrict__ dinv,
    const float* __restrict__ bnsc, const float* __restrict__ bnsh,
    const unsigned* __restrict__ btg,
    unsigned* __restrict__ hout) {
    __shared__ unsigned ybuf[16 * 68];
    const int tid = threadIdx.x;
    const int wave = tid >> 6;
    const int lane = tid & 63;
    const int cg = lane & 15;
    const int sub = lane >> 4;
    const int c8 = cg * 8;
    const char* __restrict__ hb = (const char*)hin;
    const unsigned cgo = (unsigned)(cg << 4);

    if (blockIdx.x == 0 && tid < 64) hout[(size_t)NN * 64 + tid] = 0u;

    int st[4], np[4];
    float dvv[4];
#pragma unroll
    for (int i = 0; i < 4; ++i) {
        const int v = __builtin_amdgcn_readfirstlane(blockIdx.x * 16 + wave * 4 + i);
        st[i] = offs[v];
        np[i] = (cnt[v] + 8) & ~7;
        dvv[i] = dinv[v];
    }
    const int maxp = max(max(np[0], np[1]), max(np[2], np[3]));

    f32x2 acc[4][4];
#pragma unroll
    for (int i = 0; i < 4; ++i)
#pragma unroll
        for (int j = 0; j < 4; ++j) acc[i][j] = (f32x2)0.0f;

    gather4(hb, csr, st, np, maxp, sub, cgo, acc);

    const float4 sca = *(const float4*)(bnsc + c8);
    const float4 scb = *(const float4*)(bnsc + c8 + 4);
    const float4 sha = *(const float4*)(bnsh + c8);
    const float4 shb = *(const float4*)(bnsh + c8 + 4);

#pragma unroll
    for (int i = 0; i < 4; ++i) {
#pragma unroll
        for (int j = 0; j < 4; ++j) {
            acc[i][j].x += __shfl_xor(acc[i][j].x, 16);
            acc[i][j].y += __shfl_xor(acc[i][j].y, 16);
            acc[i][j].x += __shfl_xor(acc[i][j].x, 32);
            acc[i][j].y += __shfl_xor(acc[i][j].y, 32);
        }
        if (sub == 0) {
            const float dv = dvv[i];
            const float y0 = fmaxf(dv * acc[i][0].x * sca.x + sha.x, 0.0f);
            const float y1 = fmaxf(dv * acc[i][0].y * sca.y + sha.y, 0.0f);
            const float y2 = fmaxf(dv * acc[i][1].x * sca.z + sha.z, 0.0f);
            const float y3 = fmaxf(dv * acc[i][1].y * sca.w + sha.w, 0.0f);
            const float y4 = fmaxf(dv * acc[i][2].x * scb.x + shb.x, 0.0f);
            const float y5 = fmaxf(dv * acc[i][2].y * scb.y + shb.y, 0.0f);
            const float y6 = fmaxf(dv * acc[i][3].x * scb.z + shb.z, 0.0f);
            const float y7 = fmaxf(dv * acc[i][3].y * scb.w + shb.w, 0.0f);
            *(uint4*)&ybuf[(wave * 4 + i) * 68 + cg * 4] =
                make_uint4(packbf(y0, y1), packbf(y2, y3), packbf(y4, y5), packbf(y6, y7));
        }
    }
    __syncthreads();

    // gemm tail: wave computes channel tiles t0=2*wave, t0+1 for all 16 rows
    const int nl = cg;     // row selector within block
    const int q = sub;     // k-quad
    short8 arow[4];
#pragma unroll
    for (int ks = 0; ks < 4; ++ks) {
        U4S8 cv;
        cv.u = *(const uint4*)&ybuf[nl * 68 + ks * 16 + q * 4];
        arow[ks] = cv.s;
    }
    const uint4* __restrict__ bt4 = (const uint4*)btg;
    const int t0 = wave * 2;
    f32x4 acc0 = (f32x4)0.0f, acc1 = (f32x4)0.0f;
#pragma unroll
    for (int ks = 0; ks < 4; ++ks) {
        U4S8 b0, b1;
        b0.u = bt4[((t0 + 0) * 16 + nl) * 16 + ks * 4 + q];
        b1.u = bt4[((t0 + 1) * 16 + nl) * 16 + ks * 4 + q];
        acc0 = __builtin_amdgcn_mfma_f32_16x16x32_bf16(b0.s, arow[ks], acc0, 0, 0, 0);
        acc1 = __builtin_amdgcn_mfma_f32_16x16x32_bf16(b1.s, arow[ks], acc1, 0, 0, 0);
    }
    const int rowg = blockIdx.x * 16 + nl;
    const float dsc = dinv[rowg];
    unsigned* crow = hout + (size_t)rowg * 64;
    uint2 o0, o1;
    o0.x = packbf(dsc * acc0[0], dsc * acc0[1]);
    o0.y = packbf(dsc * acc0[2], dsc * acc0[3]);
    o1.x = packbf(dsc * acc1[0], dsc * acc1[1]);
    o1.y = packbf(dsc * acc1[2], dsc * acc1[3]);
    *(uint2*)(crow + (t0 + 0) * 8 + q * 2) = o0;
    *(uint2*)(crow + (t0 + 1) * 8 + q * 2) = o1;
}

// ---------------------------------------------------------------------------
// FUSED layer-3 aggregate + BN + ReLU + mean-pool partial sums.
// ---------------------------------------------------------------------------
__global__ __launch_bounds__(256) void agg_pool_k(
    const unsigned* __restrict__ hpre, const int* __restrict__ csr,
    const int* __restrict__ offs, const int* __restrict__ cnt,
    const float* __restrict__ dinv,
    const float* __restrict__ bnsc, const float* __restrict__ bnsh,
    const int* __restrict__ batch, const int* __restrict__ flags,
    float* __restrict__ psum, int* __restrict__ gcnt) {
    __shared__ float yb[16][128];
    __shared__ int gid[16];
    const int tid = threadIdx.x;
    const int wave = tid >> 6;
    const int lane = tid & 63;
    const int cg = lane & 15;
    const int sub = lane >> 4;
    const int c8 = cg * 8;
    const char* __restrict__ hb = (const char*)hpre;
    const unsigned cgo = (unsigned)(cg << 4);
    const bool b64 = flags[1] != 0;

    int st[4], np[4];
    float dvv[4];
#pragma unroll
    for (int i = 0; i < 4; ++i) {
        const int v = __builtin_amdgcn_readfirstlane(blockIdx.x * 16 + wave * 4 + i);
        st[i] = offs[v];
        np[i] = (cnt[v] + 8) & ~7;
        dvv[i] = dinv[v];
        if (lane == 0) gid[wave * 4 + i] = b64 ? batch[2 * v] : batch[v];
    }
    const int maxp = max(max(np[0], np[1]), max(np[2], np[3]));

    f32x2 acc[4][4];
#pragma unroll
    for (int i = 0; i < 4; ++i)
#pragma unroll
        for (int j = 0; j < 4; ++j) acc[i][j] = (f32x2)0.0f;

    gather4(hb, csr, st, np, maxp, sub, cgo, acc);

    const float4 sca = *(const float4*)(bnsc + c8);
    const float4 scb = *(const float4*)(bnsc + c8 + 4);
    const float4 sha = *(const float4*)(bnsh + c8);
    const float4 shb = *(const float4*)(bnsh + c8 + 4);

#pragma unroll
    for (int i = 0; i < 4; ++i) {
#pragma unroll
        for (int j = 0; j < 4; ++j) {
            acc[i][j].x += __shfl_xor(acc[i][j].x, 16);
            acc[i][j].y += __shfl_xor(acc[i][j].y, 16);
            acc[i][j].x += __shfl_xor(acc[i][j].x, 32);
            acc[i][j].y += __shfl_xor(acc[i][j].y, 32);
        }
        if (sub == 0) {
            const float dv = dvv[i];
            const int row = wave * 4 + i;
            yb[row][c8 + 0] = fmaxf(dv * acc[i][0].x * sca.x + sha.x, 0.0f);
            yb[row][c8 + 1] = fmaxf(dv * acc[i][0].y * sca.y + sha.y, 0.0f);
            yb[row][c8 + 2] = fmaxf(dv * acc[i][1].x * sca.z + sha.z, 0.0f);
            yb[row][c8 + 3] = fmaxf(dv * acc[i][1].y * sca.w + sha.w, 0.0f);
            yb[row][c8 + 4] = fmaxf(dv * acc[i][2].x * scb.x + shb.x, 0.0f);
            yb[row][c8 + 5] = fmaxf(dv * acc[i][2].y * scb.y + shb.y, 0.0f);
            yb[row][c8 + 6] = fmaxf(dv * acc[i][3].x * scb.z + shb.z, 0.0f);
            yb[row][c8 + 7] = fmaxf(dv * acc[i][3].y * scb.w + shb.w, 0.0f);
        }
    }
    __syncthreads();

    // run-length pooled reduction (batch sorted -> few runs per block)
    if (tid < 128) {
        float s = 0.0f;
        int cur = gid[0];
        for (int r = 0; r < 16; ++r) {
            const int g = gid[r];
            if (g != cur) {
                atomicAdd(&psum[cur * HH + tid], s);
                cur = g; s = 0.0f;
            }
            s += yb[r][tid];
        }
        atomicAdd(&psum[cur * HH + tid], s);
    } else if (tid == 128) {
        int cur = gid[0], c = 0;
        for (int r = 0; r < 16; ++r) {
            const int g = gid[r];
            if (g != cur) {
                atomicAdd(&gcnt[cur], c);
                cur = g; c = 0;
            }
            ++c;
        }
        atomicAdd(&gcnt[cur], c);
    }
}

// ---------------------------------------------------------------------------
// Head: pooled = psum/cnt, then fc1+ReLU+fc2. One block per graph.
// ---------------------------------------------------------------------------
__global__ __launch_bounds__(128) void head_k(
    const float* __restrict__ psum, const int* __restrict__ gcnt,
    const float* __restrict__ fw1, const float* __restrict__ fb1,
    const float* __restrict__ fw2, const float* __restrict__ fb2,
    float* __restrict__ out) {
    __shared__ float pooled[128];
    __shared__ float hid[64];
    const int g = blockIdx.x;
    const int tid = threadIdx.x;

    const int cntn = gcnt[g];
    pooled[tid] = psum[g * HH + tid] / (float)(cntn > 0 ? cntn : 1);
    __syncthreads();

    if (tid < 64) {
        float a = fb1[tid];
#pragma unroll 4
        for (int k = 0; k < 128; ++k) a += pooled[k] * fw1[k * 64 + tid];
        hid[tid] = fmaxf(a, 0.0f);
    }
    __syncthreads();
    if (tid < 10) {
        float a = fb2[tid];
#pragma unroll
        for (int k = 0; k < 64; ++k) a += hid[k] * fw2[k * 10 + tid];
        out[g * 10 + tid] = a;
    }
}

// ---------------------------------------------------------------------------
// launch
// ---------------------------------------------------------------------------
extern "C" void kernel_launch(void* const* d_in, const int* in_sizes, int n_in,
                              void* d_out, int out_size, void* d_ws, size_t ws_size,
                              hipStream_t stream) {
    const float* x_in  = (const float*)d_in[0];
    const int*   ei    = (const int*)d_in[1];
    const int*   batch = (const int*)d_in[2];
    const float* w1 = (const float*)d_in[3];
    const float* b1 = (const float*)d_in[4];
    const float* w2 = (const float*)d_in[5];
    const float* b2 = (const float*)d_in[6];
    const float* w3 = (const float*)d_in[7];
    const float* b3 = (const float*)d_in[8];
    const float* g1 = (const float*)d_in[9];
    const float* be1 = (const float*)d_in[10];
    const float* m1 = (const float*)d_in[11];
    const float* v1 = (const float*)d_in[12];
    const float* g2 = (const float*)d_in[13];
    const float* be2 = (const float*)d_in[14];
    const float* m2 = (const float*)d_in[15];
    const float* v2 = (const float*)d_in[16];
    const float* g3 = (const float*)d_in[17];
    const float* be3 = (const float*)d_in[18];
    const float* m3 = (const float*)d_in[19];
    const float* v3 = (const float*)d_in[20];
    const float* fw1 = (const float*)d_in[21];
    const float* fb1 = (const float*)d_in[22];
    const float* fw2 = (const float*)d_in[23];
    const float* fb2 = (const float*)d_in[24];
    float* out = (float*)d_out;

    size_t off = 0;
    char* base = (char*)d_ws;
    auto alloc = [&](size_t bytes) -> void* {
        void* p = base + off;
        off += (bytes + 255) & ~(size_t)255;
        return p;
    };
    int*      degcnt = (int*)alloc((size_t)NN * 4);
    float*    dinv   = (float*)alloc((size_t)NN * 4);
    int*      offs   = (int*)alloc((size_t)NN * 4);
    int*      cursor = (int*)alloc((size_t)NBK * 4);
    int*      flags  = (int*)alloc(256);
    float*    bnsc   = (float*)alloc(3 * 128 * 4);
    float*    bnsh   = (float*)alloc(3 * 128 * 4);
    unsigned* btg    = (unsigned*)alloc(3 * 8192 * 4);            // bf16 B^T x3
    float*    psum   = (float*)alloc((size_t)GG * HH * 4);        // pooled sums f32
    int*      gcnt   = (int*)alloc((size_t)GG * 4);
    int*      csr    = (int*)alloc((size_t)NBK * CAPB * 4);
    unsigned* pairs  = (unsigned*)alloc((size_t)NBK * CAPB * 4);
    unsigned* bufA   = (unsigned*)alloc((size_t)(NN + 1) * 64 * 4);   // + sentinel row
    unsigned* bufB   = (unsigned*)alloc((size_t)(NN + 1) * 64 * 4);   // + sentinel row
    if (off > ws_size) return;

    setup_k<<<SETUP_GRID, 256, 0, stream>>>(ei, batch, w1, w2, w3,
                                            b1, g1, be1, m1, v1,
                                            b2, g2, be2, m2, v2,
                                            b3, g3, be3, m3, v3,
                                            btg, bnsc, bnsh, cursor, psum, gcnt,
                                            flags);
    passA_k<<<PASSA_WG, 256, 0, stream>>>(ei, flags, cursor, pairs);
    passB_k<<<NBK, 256, 0, stream>>>(pairs, cursor, offs, degcnt, dinv, csr);

    const int ggrid = (NN + 63) / 64;          // 1563 (covers row NN sentinel too)
    const int fgrid = NN / 16;                 // 6250 (exact)

    // L1: x @ W1 -> bufA (dinv-scaled bf16 gather table)
    gemm_mfma_k<<<ggrid, 256, 0, stream>>>(x_in, btg, dinv, bufA, NN);
    // L1 aggregate + BN1 + ReLU fused with W2 gemm -> bufB
    agg_gemm_k<<<fgrid, 256, 0, stream>>>(bufA, csr, offs, degcnt, dinv,
                                          bnsc, bnsh, btg + 8192, bufB);
    // L2 aggregate + BN2 + ReLU fused with W3 gemm -> bufA
    agg_gemm_k<<<fgrid, 256, 0, stream>>>(bufB, csr, offs, degcnt, dinv,
                                          bnsc + 128, bnsh + 128, btg + 16384, bufA);
    // L3 aggregate + BN3 + ReLU + mean-pool partials
    agg_pool_k<<<fgrid, 256, 0, stream>>>(bufA, csr, offs, degcnt, dinv,
                                          bnsc + 256, bnsh + 256, batch, flags,
                                          psum, gcnt);
    head_k<<<GG, 128, 0, stream>>>(psum, gcnt, fw1, fb1, fw2, fb2, out);
}

// Round 3
// 402.445 us; speedup vs baseline: 1.1141x; 1.1141x over previous
//
#include <hip/hip_runtime.h>
#include <math.h>

#define NN 100000
#define EE 1600000
#define GG 256
#define HH 128
#define BSH 8                 /* 256 nodes per bucket */
#define NBK 391               /* ceil(NN/256) */
#define PASSA_WG 391          /* r10-proven: 16 edges/thread */
#define CAPB 6144             /* per-bucket region: edges(~4092) + self/pad8(<=2048) */

typedef __attribute__((ext_vector_type(8))) short short8;   // 8 bf16 (4 VGPRs)
typedef __attribute__((ext_vector_type(4))) float f32x4;    // MFMA acc
typedef __attribute__((ext_vector_type(2))) float f32x2;    // packed f32 pair

union U4S8 { uint4 u; short8 s; };

// ---------------------------------------------------------------------------
// bf16 helpers (RNE pack, cheap unpack)
// ---------------------------------------------------------------------------
static __device__ __forceinline__ unsigned bf16rne(float f) {
    const unsigned u = __float_as_uint(f);
    return (u + 0x7fffu + ((u >> 16) & 1u)) >> 16;
}
static __device__ __forceinline__ unsigned packbf(float a, float b) {
    return bf16rne(a) | (bf16rne(b) << 16);
}
static __device__ __forceinline__ float bflo(unsigned u) { return __uint_as_float(u << 16); }
static __device__ __forceinline__ float bfhi(unsigned u) { return __uint_as_float(u & 0xffff0000u); }
static __device__ __forceinline__ f32x2 up2(unsigned u) {
    f32x2 r; r.x = bflo(u); r.y = bfhi(u); return r;
}

// ---------------------------------------------------------------------------
// Fused setup: wprep (ids 0..24575), bnprep (..24703), cursinit (..25094),
// psum zero (..57862), gcnt zero (..58118), dtype detect (id 58119).
// ---------------------------------------------------------------------------
__global__ __launch_bounds__(256) void setup_k(
    const int* __restrict__ ei, const int* __restrict__ batch,
    const float* __restrict__ w1, const float* __restrict__ w2,
    const float* __restrict__ w3,
    const float* __restrict__ b1, const float* __restrict__ g1,
    const float* __restrict__ be1, const float* __restrict__ m1,
    const float* __restrict__ v1,
    const float* __restrict__ b2, const float* __restrict__ g2,
    const float* __restrict__ be2, const float* __restrict__ m2,
    const float* __restrict__ v2,
    const float* __restrict__ b3, const float* __restrict__ g3,
    const float* __restrict__ be3, const float* __restrict__ m3,
    const float* __restrict__ v3,
    unsigned* __restrict__ bt, float* __restrict__ sc, float* __restrict__ sh,
    int* __restrict__ cursor, float* __restrict__ psum, int* __restrict__ gcnt,
    int* __restrict__ flags) {
    const int id = blockIdx.x * 256 + threadIdx.x;
    if (id < 24576) {
        const int w = id >> 13;
        const int rem = id & 8191;
        const int n = rem >> 6;
        const int kk = rem & 63;                      // k-pair
        const float* W = (w == 0) ? w1 : (w == 1) ? w2 : w3;
        bt[id] = packbf(W[(2 * kk) * HH + n], W[(2 * kk + 1) * HH + n]);
    } else if (id < 24704) {
        const int c = id - 24576;
        float s;
        s = g1[c] / sqrtf(v1[c] + 1e-5f);
        sc[c] = s;           sh[c] = (b1[c] - m1[c]) * s + be1[c];
        s = g2[c] / sqrtf(v2[c] + 1e-5f);
        sc[128 + c] = s;     sh[128 + c] = (b2[c] - m2[c]) * s + be2[c];
        s = g3[c] / sqrtf(v3[c] + 1e-5f);
        sc[256 + c] = s;     sh[256 + c] = (b3[c] - m3[c]) * s + be3[c];
    } else if (id < 25095) {
        const int b = id - 24704;
        cursor[b] = b * CAPB;
    } else if (id < 57863) {
        psum[id - 25095] = 0.0f;
    } else if (id < 58119) {
        gcnt[id - 57863] = 0;
    } else if (id == 58119) {
        int e64 = 1;
        for (int j = 0; j < 8; ++j) {
            if (ei[2 * EE - 1 - 2 * j] != 0) { e64 = 0; break; }
        }
        flags[0] = e64;
        flags[1] = (batch[NN - 1] == 0) ? 1 : 0;
    }
}
#define SETUP_GRID 228   /* ceil(58120/256) */

// ---------------------------------------------------------------------------
// pass A (r10 config): 391 wgs x 4096 edges (16/thread).
// ---------------------------------------------------------------------------
__global__ __launch_bounds__(256) void passA_k(const int* __restrict__ ei,
                                               const int* __restrict__ flags,
                                               int* __restrict__ cursor,
                                               unsigned* __restrict__ pairs) {
    __shared__ int h[NBK];
    __shared__ int rbase[NBK];
    const int tid = threadIdx.x;
    for (int i = tid; i < NBK; i += 256) h[i] = 0;
    __syncthreads();
    const bool e64 = flags[0] != 0;
    const int base = blockIdx.x * 4096;
    int scache[16], dcache[16];
#pragma unroll
    for (int j = 0; j < 16; ++j) {
        const int e = base + j * 256 + tid;
        int s = -1, d = 0;
        if (e < EE) {
            s = e64 ? ei[2 * e] : ei[e];
            d = e64 ? ei[2 * (EE + e)] : ei[EE + e];
            atomicAdd(&h[d >> BSH], 1);
        }
        scache[j] = s; dcache[j] = d;
    }
    __syncthreads();
    for (int i = tid; i < NBK; i += 256) {
        const int c = h[i];
        rbase[i] = c ? atomicAdd(&cursor[i], c) : 0;
    }
    __syncthreads();
    for (int i = tid; i < NBK; i += 256) h[i] = 0;
    __syncthreads();
#pragma unroll
    for (int j = 0; j < 16; ++j) {
        const int s = scache[j];
        if (s >= 0) {
            const int d = dcache[j];
            const int b = d >> BSH;
            const int r = atomicAdd(&h[b], 1);
            pairs[rbase[b] + r] = ((unsigned)(d & 255) << 17) | (unsigned)s;
        }
    }
}

// ---------------------------------------------------------------------------
// pass B (r11/r12-proven, sort reverted): one wg per bucket -> offs/degcnt/
// dinv + bucketed CSR with self-inclusive padding to a multiple of 8
// (sentinel NN = zero row). r13 ledger: src-sorting the lists bought 0 on
// the gather (fill-rate bound, not locality bound) and cost ~+40us here.
// ---------------------------------------------------------------------------
__global__ __launch_bounds__(256) void passB_k(const unsigned* __restrict__ pairs,
                                               const int* __restrict__ cursor,
                                               int* __restrict__ offs,
                                               int* __restrict__ degcnt,
                                               float* __restrict__ dinv,
                                               int* __restrict__ csr) {
    __shared__ unsigned pk[CAPB];
    __shared__ int cnt[256];
    __shared__ int loff[256];
    __shared__ int sc[256];
    const int tid = threadIdx.x;
    const int b = blockIdx.x;
    const int p0 = b * CAPB;
    const int np = cursor[b] - p0;           // real edges in bucket
    const int nb0 = b << BSH;
    const int nnode = (NN - nb0 < 256) ? (NN - nb0) : 256;

    cnt[tid] = 0;
    __syncthreads();
    for (int i = tid; i < np; i += 256) {
        const unsigned p = pairs[p0 + i];
        pk[i] = p;
        atomicAdd(&cnt[p >> 17], 1);
    }
    __syncthreads();
    const int creal = cnt[tid];
    const int cpad = (tid < nnode) ? ((creal + 8) & ~7) : 0;   // +self, pad to 8
    sc[tid] = cpad;
    __syncthreads();
    for (int off = 1; off < 256; off <<= 1) {
        int t = (tid >= off) ? sc[tid - off] : 0;
        __syncthreads();
        sc[tid] += t;
        __syncthreads();
    }
    const int ex = sc[tid] - cpad;
    loff[tid] = ex;
    if (tid < nnode) {
        const int node = nb0 + tid;
        offs[node] = p0 + ex;
        degcnt[node] = creal;
        dinv[node] = 1.0f / sqrtf((float)(creal + 1));
    }
    __syncthreads();
    cnt[tid] = 0;
    __syncthreads();
    for (int i = tid; i < np; i += 256) {
        const unsigned p = pk[i];
        const int dl = (int)(p >> 17);
        const int r = atomicAdd(&cnt[dl], 1);
        csr[p0 + loff[dl] + r] = (int)(p & 0x1FFFFu);
    }
    if (tid < nnode) {
        const int basep = p0 + loff[tid];
        csr[basep + creal] = nb0 + tid;
        for (int j = creal + 1; j < cpad; ++j) csr[basep + j] = NN;
    }
}

// ---------------------------------------------------------------------------
// Hybrid MFMA bf16 GEMM (LDS-staged B^T + direct C^T stores), verified r10.
// Used only for layer 1 (f32 input x). Row M sentinel zeroed; dinv fused.
// ---------------------------------------------------------------------------
static __device__ __forceinline__ float sani(float v) {
    if (isnan(v)) return 0.0f;
    if (isinf(v)) return v > 0.0f ? 1e6f : -1e6f;
    return v;
}

__global__ __launch_bounds__(256) void gemm_mfma_k(const float* __restrict__ Af,
                                                   const unsigned* __restrict__ btg,
                                                   const float* __restrict__ dinv,
                                                   unsigned* __restrict__ C, int M) {
    __shared__ unsigned lds_u[8704];   // B^T: 128 rows x 68 uints (34816 B)
    const int tid = threadIdx.x;
    const int wave = tid >> 6;
    const int lane = tid & 63;
    const int nl = lane & 15;
    const int q = lane >> 4;
    const int row0 = blockIdx.x * 64 + wave * 16;
    const int rowg = row0 + nl;
    const int rowa = min(rowg, M - 1);

    {
        const uint4* __restrict__ bg4 = (const uint4*)btg;
        for (int i = tid; i < 2048; i += 256) {
            const int n = i >> 4, w4 = i & 15;
            *(uint4*)&lds_u[n * 68 + w4 * 4] = bg4[n * 16 + w4];
        }
    }

    short8 a[4];
#pragma unroll
    for (int ks = 0; ks < 4; ++ks) {
        const float4 p = *(const float4*)(Af + (size_t)rowa * HH + ks * 32 + q * 8);
        const float4 r = *(const float4*)(Af + (size_t)rowa * HH + ks * 32 + q * 8 + 4);
        U4S8 cv;
        cv.u = make_uint4(packbf(sani(p.x), sani(p.y)), packbf(sani(p.z), sani(p.w)),
                          packbf(sani(r.x), sani(r.y)), packbf(sani(r.z), sani(r.w)));
        a[ks] = cv.s;
    }

    __syncthreads();   // B^T staged

    f32x4 acc[8];
#pragma unroll
    for (int t = 0; t < 8; ++t) acc[t] = (f32x4)0.0f;

    const unsigned short* __restrict__ bts = (const unsigned short*)lds_u;
#pragma unroll
    for (int ks = 0; ks < 4; ++ks) {
#pragma unroll
        for (int t = 0; t < 8; ++t) {
            const int n = t * 16 + nl;
            const short8 b = *(const short8*)(bts + n * 136 + ks * 32 + q * 8);
            acc[t] = __builtin_amdgcn_mfma_f32_16x16x32_bf16(b, a[ks], acc[t], 0, 0, 0);
        }
    }

    if (rowg < M) {
        const float dsc = dinv[rowg];
        unsigned* crow = C + (size_t)rowg * 64;
#pragma unroll
        for (int t = 0; t < 8; ++t) {
            uint2 o;
            o.x = packbf(dsc * acc[t][0], dsc * acc[t][1]);
            o.y = packbf(dsc * acc[t][2], dsc * acc[t][3]);
            *(uint2*)(crow + t * 8 + q * 2) = o;
        }
    } else if (rowg == M) {
        unsigned* crow = C + (size_t)M * 64;
#pragma unroll
        for (int t = 0; t < 8; ++t)
            *(uint2*)(crow + t * 8 + q * 2) = make_uint2(0u, 0u);
    }
}

// ---------------------------------------------------------------------------
// Interleaved 4-node gather (r12): 8 independent row-gathers in flight + 8
// csr prefetches per iteration. bf16 variant: rows are 256B (uint4/lane).
// fp8 variant: rows are 128B (uint2/lane), dequant via v_cvt_pk_f32_fp8 —
// halves per-XCD compulsory L2 fill AND halves cachelines per row.
// ---------------------------------------------------------------------------
static __device__ __forceinline__ void gather4_bf16(
    const char* __restrict__ hb, const int* __restrict__ csr,
    const int st[4], const int np[4], const int maxp,
    const int sub, const unsigned cgo, f32x2 acc[4][4]) {
    int ia[4], ib[4];
#pragma unroll
    for (int i = 0; i < 4; ++i) {
        ia[i] = csr[st[i] + sub];
        ib[i] = csr[st[i] + 4 + sub];
    }
    for (int e = 0; e < maxp; e += 8) {
        uint4 r[8];
#pragma unroll
        for (int i = 0; i < 4; ++i) {
            const bool act = (e < np[i]);                 // wave-uniform
            const unsigned sA = act ? (unsigned)ia[i] : (unsigned)NN;
            const unsigned sB = act ? (unsigned)ib[i] : (unsigned)NN;
            r[2 * i]     = *(const uint4*)(hb + ((sA << 8) | cgo));
            r[2 * i + 1] = *(const uint4*)(hb + ((sB << 8) | cgo));
        }
#pragma unroll
        for (int i = 0; i < 4; ++i) {                     // prefetch next iter
            ia[i] = csr[st[i] + e + 8 + sub];
            ib[i] = csr[st[i] + e + 12 + sub];
        }
#pragma unroll
        for (int i = 0; i < 4; ++i) {
            const uint4 rA = r[2 * i];
            const uint4 rB = r[2 * i + 1];
            acc[i][0] += up2(rA.x) + up2(rB.x);
            acc[i][1] += up2(rA.y) + up2(rB.y);
            acc[i][2] += up2(rA.z) + up2(rB.z);
            acc[i][3] += up2(rA.w) + up2(rB.w);
        }
    }
}

static __device__ __forceinline__ void gather4_fp8(
    const char* __restrict__ hb, const int* __restrict__ csr,
    const int st[4], const int np[4], const int maxp,
    const int sub, const unsigned cgo8, f32x2 acc[4][4]) {
    int ia[4], ib[4];
#pragma unroll
    for (int i = 0; i < 4; ++i) {
        ia[i] = csr[st[i] + sub];
        ib[i] = csr[st[i] + 4 + sub];
    }
    for (int e = 0; e < maxp; e += 8) {
        uint2 r[8];
#pragma unroll
        for (int i = 0; i < 4; ++i) {
            const bool act = (e < np[i]);                 // wave-uniform
            const unsigned sA = act ? (unsigned)ia[i] : (unsigned)NN;
            const unsigned sB = act ? (unsigned)ib[i] : (unsigned)NN;
            r[2 * i]     = *(const uint2*)(hb + ((sA << 7) | cgo8));
            r[2 * i + 1] = *(const uint2*)(hb + ((sB << 7) | cgo8));
        }
#pragma unroll
        for (int i = 0; i < 4; ++i) {                     // prefetch next iter
            ia[i] = csr[st[i] + e + 8 + sub];
            ib[i] = csr[st[i] + e + 12 + sub];
        }
#pragma unroll
        for (int i = 0; i < 4; ++i) {
            const uint2 rA = r[2 * i];
            const uint2 rB = r[2 * i + 1];
            acc[i][0] += __builtin_amdgcn_cvt_pk_f32_fp8(rA.x, false)
                       + __builtin_amdgcn_cvt_pk_f32_fp8(rB.x, false);
            acc[i][1] += __builtin_amdgcn_cvt_pk_f32_fp8(rA.x, true)
                       + __builtin_amdgcn_cvt_pk_f32_fp8(rB.x, true);
            acc[i][2] += __builtin_amdgcn_cvt_pk_f32_fp8(rA.y, false)
                       + __builtin_amdgcn_cvt_pk_f32_fp8(rB.y, false);
            acc[i][3] += __builtin_amdgcn_cvt_pk_f32_fp8(rA.y, true)
                       + __builtin_amdgcn_cvt_pk_f32_fp8(rB.y, true);
        }
    }
}

// ---------------------------------------------------------------------------
// FUSED aggregate(L) + gemm(L+1): block = 4 waves x 4 nodes/wave = 16 nodes.
// Templated on table dtypes: IN8 = gather table is fp8 (128B rows),
// OUT8 = write next-layer table as fp8. r14: bufB (L2 table) goes fp8 —
// per-XCD compulsory fill for the L2-agg pass halves (fill-rate-bound per
// r12/r13 evidence). Accumulation stays f32; weights/BN untouched.
// ---------------------------------------------------------------------------
template <int IN8, int OUT8>
__global__ __launch_bounds__(256) void agg_gemm_t(
    const unsigned* __restrict__ hin, const int* __restrict__ csr,
    const int* __restrict__ offs, const int* __restrict__ cnt,
    const float* __restrict__ dinv,
    const float* __restrict__ bnsc, const float* __restrict__ bnsh,
    const unsigned* __restrict__ btg,
    unsigned* __restrict__ hout) {
    __shared__ unsigned ybuf[16 * 68];
    const int tid = threadIdx.x;
    const int wave = tid >> 6;
    const int lane = tid & 63;
    const int cg = lane & 15;
    const int sub = lane >> 4;
    const int c8 = cg * 8;
    const char* __restrict__ hb = (const char*)hin;

    if (blockIdx.x == 0) {                 // zero sentinel row NN of output
        if (OUT8) { if (tid < 32) hout[(size_t)NN * 32 + tid] = 0u; }
        else      { if (tid < 64) hout[(size_t)NN * 64 + tid] = 0u; }
    }

    int st[4], np[4];
    float dvv[4];
#pragma unroll
    for (int i = 0; i < 4; ++i) {
        const int v = __builtin_amdgcn_readfirstlane(blockIdx.x * 16 + wave * 4 + i);
        st[i] = offs[v];
        np[i] = (cnt[v] + 8) & ~7;
        dvv[i] = dinv[v];
    }
    const int maxp = max(max(np[0], np[1]), max(np[2], np[3]));

    f32x2 acc[4][4];
#pragma unroll
    for (int i = 0; i < 4; ++i)
#pragma unroll
        for (int j = 0; j < 4; ++j) acc[i][j] = (f32x2)0.0f;

    if (IN8) gather4_fp8(hb, csr, st, np, maxp, sub, (unsigned)(cg << 3), acc);
    else     gather4_bf16(hb, csr, st, np, maxp, sub, (unsigned)(cg << 4), acc);

    const float4 sca = *(const float4*)(bnsc + c8);
    const float4 scb = *(const float4*)(bnsc + c8 + 4);
    const float4 sha = *(const float4*)(bnsh + c8);
    const float4 shb = *(const float4*)(bnsh + c8 + 4);

#pragma unroll
    for (int i = 0; i < 4; ++i) {
#pragma unroll
        for (int j = 0; j < 4; ++j) {
            acc[i][j].x += __shfl_xor(acc[i][j].x, 16);
            acc[i][j].y += __shfl_xor(acc[i][j].y, 16);
            acc[i][j].x += __shfl_xor(acc[i][j].x, 32);
            acc[i][j].y += __shfl_xor(acc[i][j].y, 32);
        }
        if (sub == 0) {
            const float dv = dvv[i];
            const float y0 = fmaxf(dv * acc[i][0].x * sca.x + sha.x, 0.0f);
            const float y1 = fmaxf(dv * acc[i][0].y * sca.y + sha.y, 0.0f);
            const float y2 = fmaxf(dv * acc[i][1].x * sca.z + sha.z, 0.0f);
            const float y3 = fmaxf(dv * acc[i][1].y * sca.w + sha.w, 0.0f);
            const float y4 = fmaxf(dv * acc[i][2].x * scb.x + shb.x, 0.0f);
            const float y5 = fmaxf(dv * acc[i][2].y * scb.y + shb.y, 0.0f);
            const float y6 = fmaxf(dv * acc[i][3].x * scb.z + shb.z, 0.0f);
            const float y7 = fmaxf(dv * acc[i][3].y * scb.w + shb.w, 0.0f);
            *(uint4*)&ybuf[(wave * 4 + i) * 68 + cg * 4] =
                make_uint4(packbf(y0, y1), packbf(y2, y3), packbf(y4, y5), packbf(y6, y7));
        }
    }
    __syncthreads();

    // gemm tail: wave computes channel tiles t0=2*wave, t0+1 for all 16 rows
    const int nl = cg;     // row selector within block
    const int q = sub;     // k-quad
    short8 arow[4];
#pragma unroll
    for (int ks = 0; ks < 4; ++ks) {
        U4S8 cv;
        cv.u = *(const uint4*)&ybuf[nl * 68 + ks * 16 + q * 4];
        arow[ks] = cv.s;
    }
    const uint4* __restrict__ bt4 = (const uint4*)btg;
    const int t0 = wave * 2;
    f32x4 acc0 = (f32x4)0.0f, acc1 = (f32x4)0.0f;
#pragma unroll
    for (int ks = 0; ks < 4; ++ks) {
        U4S8 b0, b1;
        b0.u = bt4[((t0 + 0) * 16 + nl) * 16 + ks * 4 + q];
        b1.u = bt4[((t0 + 1) * 16 + nl) * 16 + ks * 4 + q];
        acc0 = __builtin_amdgcn_mfma_f32_16x16x32_bf16(b0.s, arow[ks], acc0, 0, 0, 0);
        acc1 = __builtin_amdgcn_mfma_f32_16x16x32_bf16(b1.s, arow[ks], acc1, 0, 0, 0);
    }
    const int rowg = blockIdx.x * 16 + nl;
    const float dsc = dinv[rowg];
    if (OUT8) {
        // fp8 row: 128B; channel c at byte c. Tile t covers ch t*16+q*4..+4.
        char* crow = (char*)hout + (size_t)rowg * 128;
        unsigned u0 = 0, u1 = 0;
        u0 = __builtin_amdgcn_cvt_pk_fp8_f32(dsc * acc0[0], dsc * acc0[1], u0, false);
        u0 = __builtin_amdgcn_cvt_pk_fp8_f32(dsc * acc0[2], dsc * acc0[3], u0, true);
        u1 = __builtin_amdgcn_cvt_pk_fp8_f32(dsc * acc1[0], dsc * acc1[1], u1, false);
        u1 = __builtin_amdgcn_cvt_pk_fp8_f32(dsc * acc1[2], dsc * acc1[3], u1, true);
        *(unsigned*)(crow + (t0 + 0) * 16 + q * 4) = u0;
        *(unsigned*)(crow + (t0 + 1) * 16 + q * 4) = u1;
    } else {
        unsigned* crow = hout + (size_t)rowg * 64;
        uint2 o0, o1;
        o0.x = packbf(dsc * acc0[0], dsc * acc0[1]);
        o0.y = packbf(dsc * acc0[2], dsc * acc0[3]);
        o1.x = packbf(dsc * acc1[0], dsc * acc1[1]);
        o1.y = packbf(dsc * acc1[2], dsc * acc1[3]);
        *(uint2*)(crow + (t0 + 0) * 8 + q * 2) = o0;
        *(uint2*)(crow + (t0 + 1) * 8 + q * 2) = o1;
    }
}

// ---------------------------------------------------------------------------
// FUSED layer-3 aggregate + BN + ReLU + mean-pool partial sums (bf16 in).
// ---------------------------------------------------------------------------
__global__ __launch_bounds__(256) void agg_pool_k(
    const unsigned* __restrict__ hpre, const int* __restrict__ csr,
    const int* __restrict__ offs, const int* __restrict__ cnt,
    const float* __restrict__ dinv,
    const float* __restrict__ bnsc, const float* __restrict__ bnsh,
    const int* __restrict__ batch, const int* __restrict__ flags,
    float* __restrict__ psum, int* __restrict__ gcnt) {
    __shared__ float yb[16][128];
    __shared__ int gid[16];
    const int tid = threadIdx.x;
    const int wave = tid >> 6;
    const int lane = tid & 63;
    const int cg = lane & 15;
    const int sub = lane >> 4;
    const int c8 = cg * 8;
    const char* __restrict__ hb = (const char*)hpre;
    const unsigned cgo = (unsigned)(cg << 4);
    const bool b64 = flags[1] != 0;

    int st[4], np[4];
    float dvv[4];
#pragma unroll
    for (int i = 0; i < 4; ++i) {
        const int v = __builtin_amdgcn_readfirstlane(blockIdx.x * 16 + wave * 4 + i);
        st[i] = offs[v];
        np[i] = (cnt[v] + 8) & ~7;
        dvv[i] = dinv[v];
        if (lane == 0) gid[wave * 4 + i] = b64 ? batch[2 * v] : batch[v];
    }
    const int maxp = max(max(np[0], np[1]), max(np[2], np[3]));

    f32x2 acc[4][4];
#pragma unroll
    for (int i = 0; i < 4; ++i)
#pragma unroll
        for (int j = 0; j < 4; ++j) acc[i][j] = (f32x2)0.0f;

    gather4_bf16(hb, csr, st, np, maxp, sub, cgo, acc);

    const float4 sca = *(const float4*)(bnsc + c8);
    const float4 scb = *(const float4*)(bnsc + c8 + 4);
    const float4 sha = *(const float4*)(bnsh + c8);
    const float4 shb = *(const float4*)(bnsh + c8 + 4);

#pragma unroll
    for (int i = 0; i < 4; ++i) {
#pragma unroll
        for (int j = 0; j < 4; ++j) {
            acc[i][j].x += __shfl_xor(acc[i][j].x, 16);
            acc[i][j].y += __shfl_xor(acc[i][j].y, 16);
            acc[i][j].x += __shfl_xor(acc[i][j].x, 32);
            acc[i][j].y += __shfl_xor(acc[i][j].y, 32);
        }
        if (sub == 0) {
            const float dv = dvv[i];
            const int row = wave * 4 + i;
            yb[row][c8 + 0] = fmaxf(dv * acc[i][0].x * sca.x + sha.x, 0.0f);
            yb[row][c8 + 1] = fmaxf(dv * acc[i][0].y * sca.y + sha.y, 0.0f);
            yb[row][c8 + 2] = fmaxf(dv * acc[i][1].x * sca.z + sha.z, 0.0f);
            yb[row][c8 + 3] = fmaxf(dv * acc[i][1].y * sca.w + sha.w, 0.0f);
            yb[row][c8 + 4] = fmaxf(dv * acc[i][2].x * scb.x + shb.x, 0.0f);
            yb[row][c8 + 5] = fmaxf(dv * acc[i][2].y * scb.y + shb.y, 0.0f);
            yb[row][c8 + 6] = fmaxf(dv * acc[i][3].x * scb.z + shb.z, 0.0f);
            yb[row][c8 + 7] = fmaxf(dv * acc[i][3].y * scb.w + shb.w, 0.0f);
        }
    }
    __syncthreads();

    // run-length pooled reduction (batch sorted -> few runs per block)
    if (tid < 128) {
        float s = 0.0f;
        int cur = gid[0];
        for (int r = 0; r < 16; ++r) {
            const int g = gid[r];
            if (g != cur) {
                atomicAdd(&psum[cur * HH + tid], s);
                cur = g; s = 0.0f;
            }
            s += yb[r][tid];
        }
        atomicAdd(&psum[cur * HH + tid], s);
    } else if (tid == 128) {
        int cur = gid[0], c = 0;
        for (int r = 0; r < 16; ++r) {
            const int g = gid[r];
            if (g != cur) {
                atomicAdd(&gcnt[cur], c);
                cur = g; c = 0;
            }
            ++c;
        }
        atomicAdd(&gcnt[cur], c);
    }
}

// ---------------------------------------------------------------------------
// Head: pooled = psum/cnt, then fc1+ReLU+fc2. One block per graph.
// ---------------------------------------------------------------------------
__global__ __launch_bounds__(128) void head_k(
    const float* __restrict__ psum, const int* __restrict__ gcnt,
    const float* __restrict__ fw1, const float* __restrict__ fb1,
    const float* __restrict__ fw2, const float* __restrict__ fb2,
    float* __restrict__ out) {
    __shared__ float pooled[128];
    __shared__ float hid[64];
    const int g = blockIdx.x;
    const int tid = threadIdx.x;

    const int cntn = gcnt[g];
    pooled[tid] = psum[g * HH + tid] / (float)(cntn > 0 ? cntn : 1);
    __syncthreads();

    if (tid < 64) {
        float a = fb1[tid];
#pragma unroll 4
        for (int k = 0; k < 128; ++k) a += pooled[k] * fw1[k * 64 + tid];
        hid[tid] = fmaxf(a, 0.0f);
    }
    __syncthreads();
    if (tid < 10) {
        float a = fb2[tid];
#pragma unroll
        for (int k = 0; k < 64; ++k) a += hid[k] * fw2[k * 10 + tid];
        out[g * 10 + tid] = a;
    }
}

// ---------------------------------------------------------------------------
// launch
// ---------------------------------------------------------------------------
extern "C" void kernel_launch(void* const* d_in, const int* in_sizes, int n_in,
                              void* d_out, int out_size, void* d_ws, size_t ws_size,
                              hipStream_t stream) {
    const float* x_in  = (const float*)d_in[0];
    const int*   ei    = (const int*)d_in[1];
    const int*   batch = (const int*)d_in[2];
    const float* w1 = (const float*)d_in[3];
    const float* b1 = (const float*)d_in[4];
    const float* w2 = (const float*)d_in[5];
    const float* b2 = (const float*)d_in[6];
    const float* w3 = (const float*)d_in[7];
    const float* b3 = (const float*)d_in[8];
    const float* g1 = (const float*)d_in[9];
    const float* be1 = (const float*)d_in[10];
    const float* m1 = (const float*)d_in[11];
    const float* v1 = (const float*)d_in[12];
    const float* g2 = (const float*)d_in[13];
    const float* be2 = (const float*)d_in[14];
    const float* m2 = (const float*)d_in[15];
    const float* v2 = (const float*)d_in[16];
    const float* g3 = (const float*)d_in[17];
    const float* be3 = (const float*)d_in[18];
    const float* m3 = (const float*)d_in[19];
    const float* v3 = (const float*)d_in[20];
    const float* fw1 = (const float*)d_in[21];
    const float* fb1 = (const float*)d_in[22];
    const float* fw2 = (const float*)d_in[23];
    const float* fb2 = (const float*)d_in[24];
    float* out = (float*)d_out;

    size_t off = 0;
    char* base = (char*)d_ws;
    auto alloc = [&](size_t bytes) -> void* {
        void* p = base + off;
        off += (bytes + 255) & ~(size_t)255;
        return p;
    };
    int*      degcnt = (int*)alloc((size_t)NN * 4);
    float*    dinv   = (float*)alloc((size_t)NN * 4);
    int*      offs   = (int*)alloc((size_t)NN * 4);
    int*      cursor = (int*)alloc((size_t)NBK * 4);
    int*      flags  = (int*)alloc(256);
    float*    bnsc   = (float*)alloc(3 * 128 * 4);
    float*    bnsh   = (float*)alloc(3 * 128 * 4);
    unsigned* btg    = (unsigned*)alloc(3 * 8192 * 4);            // bf16 B^T x3
    float*    psum   = (float*)alloc((size_t)GG * HH * 4);        // pooled sums f32
    int*      gcnt   = (int*)alloc((size_t)GG * 4);
    int*      csr    = (int*)alloc((size_t)NBK * CAPB * 4);
    unsigned* pairs  = (unsigned*)alloc((size_t)NBK * CAPB * 4);
    unsigned* bufA   = (unsigned*)alloc((size_t)(NN + 1) * 64 * 4);   // bf16 + sentinel
    unsigned* bufB   = (unsigned*)alloc((size_t)(NN + 1) * 32 * 4);   // fp8 + sentinel
    if (off > ws_size) return;

    setup_k<<<SETUP_GRID, 256, 0, stream>>>(ei, batch, w1, w2, w3,
                                            b1, g1, be1, m1, v1,
                                            b2, g2, be2, m2, v2,
                                            b3, g3, be3, m3, v3,
                                            btg, bnsc, bnsh, cursor, psum, gcnt,
                                            flags);
    passA_k<<<PASSA_WG, 256, 0, stream>>>(ei, flags, cursor, pairs);
    passB_k<<<NBK, 256, 0, stream>>>(pairs, cursor, offs, degcnt, dinv, csr);

    const int ggrid = (NN + 63) / 64;          // 1563 (covers row NN sentinel too)
    const int fgrid = NN / 16;                 // 6250 (exact)

    // L1: x @ W1 -> bufA (dinv-scaled bf16 gather table)
    gemm_mfma_k<<<ggrid, 256, 0, stream>>>(x_in, btg, dinv, bufA, NN);
    // L1 aggregate + BN1 + ReLU fused with W2 gemm -> bufB (fp8 table)
    agg_gemm_t<0, 1><<<fgrid, 256, 0, stream>>>(bufA, csr, offs, degcnt, dinv,
                                                bnsc, bnsh, btg + 8192, bufB);
    // L2 aggregate (fp8 gather) + BN2 + ReLU fused with W3 gemm -> bufA (bf16)
    agg_gemm_t<1, 0><<<fgrid, 256, 0, stream>>>(bufB, csr, offs, degcnt, dinv,
                                                bnsc + 128, bnsh + 128, btg + 16384, bufA);
    // L3 aggregate + BN3 + ReLU + mean-pool partials
    agg_pool_k<<<fgrid, 256, 0, stream>>>(bufA, csr, offs, degcnt, dinv,
                                          bnsc + 256, bnsh + 256, batch, flags,
                                          psum, gcnt);
    head_k<<<GG, 128, 0, stream>>>(psum, gcnt, fw1, fb1, fw2, fb2, out);
}

// Round 4
// 385.887 us; speedup vs baseline: 1.1619x; 1.0429x over previous
//
#include <hip/hip_runtime.h>
#include <math.h>

#define NN 100000
#define EE 1600000
#define GG 256
#define HH 128
#define BSH 8                 /* 256 nodes per bucket */
#define NBK 391               /* ceil(NN/256) */
#define PASSA_WG 391          /* r10-proven: 16 edges/thread */
#define CAPB 6144             /* per-bucket region: edges(~4092) + self/pad8(<=2048) */

typedef __attribute__((ext_vector_type(8))) short short8;   // 8 bf16 (4 VGPRs)
typedef __attribute__((ext_vector_type(4))) float f32x4;    // MFMA acc
typedef __attribute__((ext_vector_type(2))) float f32x2;    // packed f32 pair

union U4S8 { uint4 u; short8 s; };

// ---------------------------------------------------------------------------
// bf16 helpers (RNE pack, cheap unpack)
// ---------------------------------------------------------------------------
static __device__ __forceinline__ unsigned bf16rne(float f) {
    const unsigned u = __float_as_uint(f);
    return (u + 0x7fffu + ((u >> 16) & 1u)) >> 16;
}
static __device__ __forceinline__ unsigned packbf(float a, float b) {
    return bf16rne(a) | (bf16rne(b) << 16);
}
static __device__ __forceinline__ float bflo(unsigned u) { return __uint_as_float(u << 16); }
static __device__ __forceinline__ float bfhi(unsigned u) { return __uint_as_float(u & 0xffff0000u); }

// ---------------------------------------------------------------------------
// Fused setup: wprep (ids 0..24575), bnprep (..24703), cursinit (..25094),
// psum zero (..57862), gcnt zero (..58118), dtype detect (id 58119).
// ---------------------------------------------------------------------------
__global__ __launch_bounds__(256) void setup_k(
    const int* __restrict__ ei, const int* __restrict__ batch,
    const float* __restrict__ w1, const float* __restrict__ w2,
    const float* __restrict__ w3,
    const float* __restrict__ b1, const float* __restrict__ g1,
    const float* __restrict__ be1, const float* __restrict__ m1,
    const float* __restrict__ v1,
    const float* __restrict__ b2, const float* __restrict__ g2,
    const float* __restrict__ be2, const float* __restrict__ m2,
    const float* __restrict__ v2,
    const float* __restrict__ b3, const float* __restrict__ g3,
    const float* __restrict__ be3, const float* __restrict__ m3,
    const float* __restrict__ v3,
    unsigned* __restrict__ bt, float* __restrict__ sc, float* __restrict__ sh,
    int* __restrict__ cursor, float* __restrict__ psum, int* __restrict__ gcnt,
    int* __restrict__ flags) {
    const int id = blockIdx.x * 256 + threadIdx.x;
    if (id < 24576) {
        const int w = id >> 13;
        const int rem = id & 8191;
        const int n = rem >> 6;
        const int kk = rem & 63;                      // k-pair
        const float* W = (w == 0) ? w1 : (w == 1) ? w2 : w3;
        bt[id] = packbf(W[(2 * kk) * HH + n], W[(2 * kk + 1) * HH + n]);
    } else if (id < 24704) {
        const int c = id - 24576;
        float s;
        s = g1[c] / sqrtf(v1[c] + 1e-5f);
        sc[c] = s;           sh[c] = (b1[c] - m1[c]) * s + be1[c];
        s = g2[c] / sqrtf(v2[c] + 1e-5f);
        sc[128 + c] = s;     sh[128 + c] = (b2[c] - m2[c]) * s + be2[c];
        s = g3[c] / sqrtf(v3[c] + 1e-5f);
        sc[256 + c] = s;     sh[256 + c] = (b3[c] - m3[c]) * s + be3[c];
    } else if (id < 25095) {
        const int b = id - 24704;
        cursor[b] = b * CAPB;
    } else if (id < 57863) {
        psum[id - 25095] = 0.0f;
    } else if (id < 58119) {
        gcnt[id - 57863] = 0;
    } else if (id == 58119) {
        int e64 = 1;
        for (int j = 0; j < 8; ++j) {
            if (ei[2 * EE - 1 - 2 * j] != 0) { e64 = 0; break; }
        }
        flags[0] = e64;
        flags[1] = (batch[NN - 1] == 0) ? 1 : 0;
    }
}
#define SETUP_GRID 228   /* ceil(58120/256) */

// ---------------------------------------------------------------------------
// pass A (r10 config): 391 wgs x 4096 edges (16/thread).
// ---------------------------------------------------------------------------
__global__ __launch_bounds__(256) void passA_k(const int* __restrict__ ei,
                                               const int* __restrict__ flags,
                                               int* __restrict__ cursor,
                                               unsigned* __restrict__ pairs) {
    __shared__ int h[NBK];
    __shared__ int rbase[NBK];
    const int tid = threadIdx.x;
    for (int i = tid; i < NBK; i += 256) h[i] = 0;
    __syncthreads();
    const bool e64 = flags[0] != 0;
    const int base = blockIdx.x * 4096;
    int scache[16], dcache[16];
#pragma unroll
    for (int j = 0; j < 16; ++j) {
        const int e = base + j * 256 + tid;
        int s = -1, d = 0;
        if (e < EE) {
            s = e64 ? ei[2 * e] : ei[e];
            d = e64 ? ei[2 * (EE + e)] : ei[EE + e];
            atomicAdd(&h[d >> BSH], 1);
        }
        scache[j] = s; dcache[j] = d;
    }
    __syncthreads();
    for (int i = tid; i < NBK; i += 256) {
        const int c = h[i];
        rbase[i] = c ? atomicAdd(&cursor[i], c) : 0;
    }
    __syncthreads();
    for (int i = tid; i < NBK; i += 256) h[i] = 0;
    __syncthreads();
#pragma unroll
    for (int j = 0; j < 16; ++j) {
        const int s = scache[j];
        if (s >= 0) {
            const int d = dcache[j];
            const int b = d >> BSH;
            const int r = atomicAdd(&h[b], 1);
            pairs[rbase[b] + r] = ((unsigned)(d & 255) << 17) | (unsigned)s;
        }
    }
}

// ---------------------------------------------------------------------------
// pass B (r11/r12-proven): one wg per bucket -> offs/degcnt/dinv + bucketed
// CSR, self-inclusive padding to a multiple of 8 (sentinel NN = zero row).
// ---------------------------------------------------------------------------
__global__ __launch_bounds__(256) void passB_k(const unsigned* __restrict__ pairs,
                                               const int* __restrict__ cursor,
                                               int* __restrict__ offs,
                                               int* __restrict__ degcnt,
                                               float* __restrict__ dinv,
                                               int* __restrict__ csr) {
    __shared__ unsigned pk[CAPB];
    __shared__ int cnt[256];
    __shared__ int loff[256];
    __shared__ int sc[256];
    const int tid = threadIdx.x;
    const int b = blockIdx.x;
    const int p0 = b * CAPB;
    const int np = cursor[b] - p0;           // real edges in bucket
    const int nb0 = b << BSH;
    const int nnode = (NN - nb0 < 256) ? (NN - nb0) : 256;

    cnt[tid] = 0;
    __syncthreads();
    for (int i = tid; i < np; i += 256) {
        const unsigned p = pairs[p0 + i];
        pk[i] = p;
        atomicAdd(&cnt[p >> 17], 1);
    }
    __syncthreads();
    const int creal = cnt[tid];
    const int cpad = (tid < nnode) ? ((creal + 8) & ~7) : 0;   // +self, pad to 8
    sc[tid] = cpad;
    __syncthreads();
    for (int off = 1; off < 256; off <<= 1) {
        int t = (tid >= off) ? sc[tid - off] : 0;
        __syncthreads();
        sc[tid] += t;
        __syncthreads();
    }
    const int ex = sc[tid] - cpad;
    loff[tid] = ex;
    if (tid < nnode) {
        const int node = nb0 + tid;
        offs[node] = p0 + ex;
        degcnt[node] = creal;
        dinv[node] = 1.0f / sqrtf((float)(creal + 1));
    }
    __syncthreads();
    cnt[tid] = 0;
    __syncthreads();
    for (int i = tid; i < np; i += 256) {
        const unsigned p = pk[i];
        const int dl = (int)(p >> 17);
        const int r = atomicAdd(&cnt[dl], 1);
        csr[p0 + loff[dl] + r] = (int)(p & 0x1FFFFu);
    }
    if (tid < nnode) {
        const int basep = p0 + loff[tid];
        csr[basep + creal] = nb0 + tid;
        for (int j = creal + 1; j < cpad; ++j) csr[basep + j] = NN;
    }
}

// ---------------------------------------------------------------------------
// Hybrid MFMA bf16 GEMM (LDS-staged B^T), layer 1 only (f32 input x).
// r14: output table now fp8 e4m3 (128B rows) — all gather tables are fp8,
// halving per-XCD compulsory L2 fill (gather passes are a+b*lines bound).
// Row M sentinel zeroed; dinv fused into the stored values.
// ---------------------------------------------------------------------------
static __device__ __forceinline__ float sani(float v) {
    if (isnan(v)) return 0.0f;
    if (isinf(v)) return v > 0.0f ? 1e6f : -1e6f;
    return v;
}

__global__ __launch_bounds__(256) void gemm_mfma_k(const float* __restrict__ Af,
                                                   const unsigned* __restrict__ btg,
                                                   const float* __restrict__ dinv,
                                                   unsigned* __restrict__ C, int M) {
    __shared__ unsigned lds_u[8704];   // B^T: 128 rows x 68 uints (34816 B)
    const int tid = threadIdx.x;
    const int wave = tid >> 6;
    const int lane = tid & 63;
    const int nl = lane & 15;
    const int q = lane >> 4;
    const int row0 = blockIdx.x * 64 + wave * 16;
    const int rowg = row0 + nl;
    const int rowa = min(rowg, M - 1);

    {
        const uint4* __restrict__ bg4 = (const uint4*)btg;
        for (int i = tid; i < 2048; i += 256) {
            const int n = i >> 4, w4 = i & 15;
            *(uint4*)&lds_u[n * 68 + w4 * 4] = bg4[n * 16 + w4];
        }
    }

    short8 a[4];
#pragma unroll
    for (int ks = 0; ks < 4; ++ks) {
        const float4 p = *(const float4*)(Af + (size_t)rowa * HH + ks * 32 + q * 8);
        const float4 r = *(const float4*)(Af + (size_t)rowa * HH + ks * 32 + q * 8 + 4);
        U4S8 cv;
        cv.u = make_uint4(packbf(sani(p.x), sani(p.y)), packbf(sani(p.z), sani(p.w)),
                          packbf(sani(r.x), sani(r.y)), packbf(sani(r.z), sani(r.w)));
        a[ks] = cv.s;
    }

    __syncthreads();   // B^T staged

    f32x4 acc[8];
#pragma unroll
    for (int t = 0; t < 8; ++t) acc[t] = (f32x4)0.0f;

    const unsigned short* __restrict__ bts = (const unsigned short*)lds_u;
#pragma unroll
    for (int ks = 0; ks < 4; ++ks) {
#pragma unroll
        for (int t = 0; t < 8; ++t) {
            const int n = t * 16 + nl;
            const short8 b = *(const short8*)(bts + n * 136 + ks * 32 + q * 8);
            acc[t] = __builtin_amdgcn_mfma_f32_16x16x32_bf16(b, a[ks], acc[t], 0, 0, 0);
        }
    }

    if (rowg < M) {
        const float dsc = dinv[rowg];
        char* crow = (char*)C + (size_t)rowg * 128;
#pragma unroll
        for (int t = 0; t < 8; ++t) {
            unsigned u = 0;
            u = __builtin_amdgcn_cvt_pk_fp8_f32(dsc * acc[t][0], dsc * acc[t][1], u, false);
            u = __builtin_amdgcn_cvt_pk_fp8_f32(dsc * acc[t][2], dsc * acc[t][3], u, true);
            *(unsigned*)(crow + t * 16 + q * 4) = u;
        }
    } else if (rowg == M) {
        char* crow = (char*)C + (size_t)M * 128;
#pragma unroll
        for (int t = 0; t < 8; ++t)
            *(unsigned*)(crow + t * 16 + q * 4) = 0u;
    }
}

// ---------------------------------------------------------------------------
// Interleaved 4-node fp8 gather (r14): rows are 128B (uint2/lane, 2 L2
// lines/row). csr indices are now PACKED: lane sub owns edges
// {e+2*sub, e+2*sub+1}, fetched as ONE int2 load -> per-8-edge iteration
// the VMEM count drops 16 -> 12 (8 row gathers + 4 csr int2 prefetches).
// Dequant via v_cvt_pk_f32_fp8. Nodes past npad read zeroed sentinel NN.
// ---------------------------------------------------------------------------
static __device__ __forceinline__ void gather4_fp8(
    const char* __restrict__ hb, const int* __restrict__ csr,
    const int st[4], const int np[4], const int maxp,
    const int sub, const unsigned cgo8, f32x2 acc[4][4]) {
    int2 ic[4];
#pragma unroll
    for (int i = 0; i < 4; ++i)
        ic[i] = *(const int2*)&csr[st[i] + 2 * sub];
    for (int e = 0; e < maxp; e += 8) {
        uint2 r[8];
#pragma unroll
        for (int i = 0; i < 4; ++i) {
            const bool act = (e < np[i]);                 // wave-uniform
            const unsigned sA = act ? (unsigned)ic[i].x : (unsigned)NN;
            const unsigned sB = act ? (unsigned)ic[i].y : (unsigned)NN;
            r[2 * i]     = *(const uint2*)(hb + ((sA << 7) | cgo8));
            r[2 * i + 1] = *(const uint2*)(hb + ((sB << 7) | cgo8));
        }
#pragma unroll
        for (int i = 0; i < 4; ++i)                       // prefetch next iter
            ic[i] = *(const int2*)&csr[st[i] + e + 8 + 2 * sub];
#pragma unroll
        for (int i = 0; i < 4; ++i) {
            const uint2 rA = r[2 * i];
            const uint2 rB = r[2 * i + 1];
            acc[i][0] += __builtin_amdgcn_cvt_pk_f32_fp8(rA.x, false)
                       + __builtin_amdgcn_cvt_pk_f32_fp8(rB.x, false);
            acc[i][1] += __builtin_amdgcn_cvt_pk_f32_fp8(rA.x, true)
                       + __builtin_amdgcn_cvt_pk_f32_fp8(rB.x, true);
            acc[i][2] += __builtin_amdgcn_cvt_pk_f32_fp8(rA.y, false)
                       + __builtin_amdgcn_cvt_pk_f32_fp8(rB.y, false);
            acc[i][3] += __builtin_amdgcn_cvt_pk_f32_fp8(rA.y, true)
                       + __builtin_amdgcn_cvt_pk_f32_fp8(rB.y, true);
        }
    }
}

// ---------------------------------------------------------------------------
// FUSED aggregate(L) + gemm(L+1): block = 4 waves x 4 nodes/wave = 16 nodes.
// fp8 gather table in, fp8 gather table out. Accumulation f32; weights bf16
// (MFMA); BN f32. Output sentinel row NN zeroed by block 0.
// ---------------------------------------------------------------------------
__global__ __launch_bounds__(256) void agg_gemm_k(
    const unsigned* __restrict__ hin, const int* __restrict__ csr,
    const int* __restrict__ offs, const int* __restrict__ cnt,
    const float* __restrict__ dinv,
    const float* __restrict__ bnsc, const float* __restrict__ bnsh,
    const unsigned* __restrict__ btg,
    unsigned* __restrict__ hout) {
    __shared__ unsigned ybuf[16 * 68];
    const int tid = threadIdx.x;
    const int wave = tid >> 6;
    const int lane = tid & 63;
    const int cg = lane & 15;
    const int sub = lane >> 4;
    const int c8 = cg * 8;
    const char* __restrict__ hb = (const char*)hin;

    if (blockIdx.x == 0 && tid < 32) hout[(size_t)NN * 32 + tid] = 0u;

    int st[4], np[4];
    float dvv[4];
#pragma unroll
    for (int i = 0; i < 4; ++i) {
        const int v = __builtin_amdgcn_readfirstlane(blockIdx.x * 16 + wave * 4 + i);
        st[i] = offs[v];
        np[i] = (cnt[v] + 8) & ~7;
        dvv[i] = dinv[v];
    }
    const int maxp = max(max(np[0], np[1]), max(np[2], np[3]));

    f32x2 acc[4][4];
#pragma unroll
    for (int i = 0; i < 4; ++i)
#pragma unroll
        for (int j = 0; j < 4; ++j) acc[i][j] = (f32x2)0.0f;

    gather4_fp8(hb, csr, st, np, maxp, sub, (unsigned)(cg << 3), acc);

    const float4 sca = *(const float4*)(bnsc + c8);
    const float4 scb = *(const float4*)(bnsc + c8 + 4);
    const float4 sha = *(const float4*)(bnsh + c8);
    const float4 shb = *(const float4*)(bnsh + c8 + 4);

#pragma unroll
    for (int i = 0; i < 4; ++i) {
#pragma unroll
        for (int j = 0; j < 4; ++j) {
            acc[i][j].x += __shfl_xor(acc[i][j].x, 16);
            acc[i][j].y += __shfl_xor(acc[i][j].y, 16);
            acc[i][j].x += __shfl_xor(acc[i][j].x, 32);
            acc[i][j].y += __shfl_xor(acc[i][j].y, 32);
        }
        if (sub == 0) {
            const float dv = dvv[i];
            const float y0 = fmaxf(dv * acc[i][0].x * sca.x + sha.x, 0.0f);
            const float y1 = fmaxf(dv * acc[i][0].y * sca.y + sha.y, 0.0f);
            const float y2 = fmaxf(dv * acc[i][1].x * sca.z + sha.z, 0.0f);
            const float y3 = fmaxf(dv * acc[i][1].y * sca.w + sha.w, 0.0f);
            const float y4 = fmaxf(dv * acc[i][2].x * scb.x + shb.x, 0.0f);
            const float y5 = fmaxf(dv * acc[i][2].y * scb.y + shb.y, 0.0f);
            const float y6 = fmaxf(dv * acc[i][3].x * scb.z + shb.z, 0.0f);
            const float y7 = fmaxf(dv * acc[i][3].y * scb.w + shb.w, 0.0f);
            *(uint4*)&ybuf[(wave * 4 + i) * 68 + cg * 4] =
                make_uint4(packbf(y0, y1), packbf(y2, y3), packbf(y4, y5), packbf(y6, y7));
        }
    }
    __syncthreads();

    // gemm tail: wave computes channel tiles t0=2*wave, t0+1 for all 16 rows
    const int nl = cg;     // row selector within block
    const int q = sub;     // k-quad
    short8 arow[4];
#pragma unroll
    for (int ks = 0; ks < 4; ++ks) {
        U4S8 cv;
        cv.u = *(const uint4*)&ybuf[nl * 68 + ks * 16 + q * 4];
        arow[ks] = cv.s;
    }
    const uint4* __restrict__ bt4 = (const uint4*)btg;
    const int t0 = wave * 2;
    f32x4 acc0 = (f32x4)0.0f, acc1 = (f32x4)0.0f;
#pragma unroll
    for (int ks = 0; ks < 4; ++ks) {
        U4S8 b0, b1;
        b0.u = bt4[((t0 + 0) * 16 + nl) * 16 + ks * 4 + q];
        b1.u = bt4[((t0 + 1) * 16 + nl) * 16 + ks * 4 + q];
        acc0 = __builtin_amdgcn_mfma_f32_16x16x32_bf16(b0.s, arow[ks], acc0, 0, 0, 0);
        acc1 = __builtin_amdgcn_mfma_f32_16x16x32_bf16(b1.s, arow[ks], acc1, 0, 0, 0);
    }
    const int rowg = blockIdx.x * 16 + nl;
    const float dsc = dinv[rowg];
    // fp8 row: 128B; channel c at byte c. Tile t covers ch t*16+q*4..+3.
    char* crow = (char*)hout + (size_t)rowg * 128;
    unsigned u0 = 0, u1 = 0;
    u0 = __builtin_amdgcn_cvt_pk_fp8_f32(dsc * acc0[0], dsc * acc0[1], u0, false);
    u0 = __builtin_amdgcn_cvt_pk_fp8_f32(dsc * acc0[2], dsc * acc0[3], u0, true);
    u1 = __builtin_amdgcn_cvt_pk_fp8_f32(dsc * acc1[0], dsc * acc1[1], u1, false);
    u1 = __builtin_amdgcn_cvt_pk_fp8_f32(dsc * acc1[2], dsc * acc1[3], u1, true);
    *(unsigned*)(crow + (t0 + 0) * 16 + q * 4) = u0;
    *(unsigned*)(crow + (t0 + 1) * 16 + q * 4) = u1;
}

// ---------------------------------------------------------------------------
// FUSED layer-3 aggregate + BN + ReLU + mean-pool partial sums (fp8 in).
// ---------------------------------------------------------------------------
__global__ __launch_bounds__(256) void agg_pool_k(
    const unsigned* __restrict__ hpre, const int* __restrict__ csr,
    const int* __restrict__ offs, const int* __restrict__ cnt,
    const float* __restrict__ dinv,
    const float* __restrict__ bnsc, const float* __restrict__ bnsh,
    const int* __restrict__ batch, const int* __restrict__ flags,
    float* __restrict__ psum, int* __restrict__ gcnt) {
    __shared__ float yb[16][128];
    __shared__ int gid[16];
    const int tid = threadIdx.x;
    const int wave = tid >> 6;
    const int lane = tid & 63;
    const int cg = lane & 15;
    const int sub = lane >> 4;
    const int c8 = cg * 8;
    const char* __restrict__ hb = (const char*)hpre;
    const bool b64 = flags[1] != 0;

    int st[4], np[4];
    float dvv[4];
#pragma unroll
    for (int i = 0; i < 4; ++i) {
        const int v = __builtin_amdgcn_readfirstlane(blockIdx.x * 16 + wave * 4 + i);
        st[i] = offs[v];
        np[i] = (cnt[v] + 8) & ~7;
        dvv[i] = dinv[v];
        if (lane == 0) gid[wave * 4 + i] = b64 ? batch[2 * v] : batch[v];
    }
    const int maxp = max(max(np[0], np[1]), max(np[2], np[3]));

    f32x2 acc[4][4];
#pragma unroll
    for (int i = 0; i < 4; ++i)
#pragma unroll
        for (int j = 0; j < 4; ++j) acc[i][j] = (f32x2)0.0f;

    gather4_fp8(hb, csr, st, np, maxp, sub, (unsigned)(cg << 3), acc);

    const float4 sca = *(const float4*)(bnsc + c8);
    const float4 scb = *(const float4*)(bnsc + c8 + 4);
    const float4 sha = *(const float4*)(bnsh + c8);
    const float4 shb = *(const float4*)(bnsh + c8 + 4);

#pragma unroll
    for (int i = 0; i < 4; ++i) {
#pragma unroll
        for (int j = 0; j < 4; ++j) {
            acc[i][j].x += __shfl_xor(acc[i][j].x, 16);
            acc[i][j].y += __shfl_xor(acc[i][j].y, 16);
            acc[i][j].x += __shfl_xor(acc[i][j].x, 32);
            acc[i][j].y += __shfl_xor(acc[i][j].y, 32);
        }
        if (sub == 0) {
            const float dv = dvv[i];
            const int row = wave * 4 + i;
            yb[row][c8 + 0] = fmaxf(dv * acc[i][0].x * sca.x + sha.x, 0.0f);
            yb[row][c8 + 1] = fmaxf(dv * acc[i][0].y * sca.y + sha.y, 0.0f);
            yb[row][c8 + 2] = fmaxf(dv * acc[i][1].x * sca.z + sha.z, 0.0f);
            yb[row][c8 + 3] = fmaxf(dv * acc[i][1].y * sca.w + sha.w, 0.0f);
            yb[row][c8 + 4] = fmaxf(dv * acc[i][2].x * scb.x + shb.x, 0.0f);
            yb[row][c8 + 5] = fmaxf(dv * acc[i][2].y * scb.y + shb.y, 0.0f);
            yb[row][c8 + 6] = fmaxf(dv * acc[i][3].x * scb.z + shb.z, 0.0f);
            yb[row][c8 + 7] = fmaxf(dv * acc[i][3].y * scb.w + shb.w, 0.0f);
        }
    }
    __syncthreads();

    // run-length pooled reduction (batch sorted -> few runs per block)
    if (tid < 128) {
        float s = 0.0f;
        int cur = gid[0];
        for (int r = 0; r < 16; ++r) {
            const int g = gid[r];
            if (g != cur) {
                atomicAdd(&psum[cur * HH + tid], s);
                cur = g; s = 0.0f;
            }
            s += yb[r][tid];
        }
        atomicAdd(&psum[cur * HH + tid], s);
    } else if (tid == 128) {
        int cur = gid[0], c = 0;
        for (int r = 0; r < 16; ++r) {
            const int g = gid[r];
            if (g != cur) {
                atomicAdd(&gcnt[cur], c);
                cur = g; c = 0;
            }
            ++c;
        }
        atomicAdd(&gcnt[cur], c);
    }
}

// ---------------------------------------------------------------------------
// Head: pooled = psum/cnt, then fc1+ReLU+fc2. One block per graph.
// ---------------------------------------------------------------------------
__global__ __launch_bounds__(128) void head_k(
    const float* __restrict__ psum, const int* __restrict__ gcnt,
    const float* __restrict__ fw1, const float* __restrict__ fb1,
    const float* __restrict__ fw2, const float* __restrict__ fb2,
    float* __restrict__ out) {
    __shared__ float pooled[128];
    __shared__ float hid[64];
    const int g = blockIdx.x;
    const int tid = threadIdx.x;

    const int cntn = gcnt[g];
    pooled[tid] = psum[g * HH + tid] / (float)(cntn > 0 ? cntn : 1);
    __syncthreads();

    if (tid < 64) {
        float a = fb1[tid];
#pragma unroll 4
        for (int k = 0; k < 128; ++k) a += pooled[k] * fw1[k * 64 + tid];
        hid[tid] = fmaxf(a, 0.0f);
    }
    __syncthreads();
    if (tid < 10) {
        float a = fb2[tid];
#pragma unroll
        for (int k = 0; k < 64; ++k) a += hid[k] * fw2[k * 10 + tid];
        out[g * 10 + tid] = a;
    }
}

// ---------------------------------------------------------------------------
// launch
// ---------------------------------------------------------------------------
extern "C" void kernel_launch(void* const* d_in, const int* in_sizes, int n_in,
                              void* d_out, int out_size, void* d_ws, size_t ws_size,
                              hipStream_t stream) {
    const float* x_in  = (const float*)d_in[0];
    const int*   ei    = (const int*)d_in[1];
    const int*   batch = (const int*)d_in[2];
    const float* w1 = (const float*)d_in[3];
    const float* b1 = (const float*)d_in[4];
    const float* w2 = (const float*)d_in[5];
    const float* b2 = (const float*)d_in[6];
    const float* w3 = (const float*)d_in[7];
    const float* b3 = (const float*)d_in[8];
    const float* g1 = (const float*)d_in[9];
    const float* be1 = (const float*)d_in[10];
    const float* m1 = (const float*)d_in[11];
    const float* v1 = (const float*)d_in[12];
    const float* g2 = (const float*)d_in[13];
    const float* be2 = (const float*)d_in[14];
    const float* m2 = (const float*)d_in[15];
    const float* v2 = (const float*)d_in[16];
    const float* g3 = (const float*)d_in[17];
    const float* be3 = (const float*)d_in[18];
    const float* m3 = (const float*)d_in[19];
    const float* v3 = (const float*)d_in[20];
    const float* fw1 = (const float*)d_in[21];
    const float* fb1 = (const float*)d_in[22];
    const float* fw2 = (const float*)d_in[23];
    const float* fb2 = (const float*)d_in[24];
    float* out = (float*)d_out;

    size_t off = 0;
    char* base = (char*)d_ws;
    auto alloc = [&](size_t bytes) -> void* {
        void* p = base + off;
        off += (bytes + 255) & ~(size_t)255;
        return p;
    };
    int*      degcnt = (int*)alloc((size_t)NN * 4);
    float*    dinv   = (float*)alloc((size_t)NN * 4);
    int*      offs   = (int*)alloc((size_t)NN * 4);
    int*      cursor = (int*)alloc((size_t)NBK * 4);
    int*      flags  = (int*)alloc(256);
    float*    bnsc   = (float*)alloc(3 * 128 * 4);
    float*    bnsh   = (float*)alloc(3 * 128 * 4);
    unsigned* btg    = (unsigned*)alloc(3 * 8192 * 4);            // bf16 B^T x3
    float*    psum   = (float*)alloc((size_t)GG * HH * 4);        // pooled sums f32
    int*      gcnt   = (int*)alloc((size_t)GG * 4);
    int*      csr    = (int*)alloc((size_t)NBK * CAPB * 4);
    unsigned* pairs  = (unsigned*)alloc((size_t)NBK * CAPB * 4);
    unsigned* bufA   = (unsigned*)alloc((size_t)(NN + 1) * 32 * 4);   // fp8 + sentinel
    unsigned* bufB   = (unsigned*)alloc((size_t)(NN + 1) * 32 * 4);   // fp8 + sentinel
    if (off > ws_size) return;

    setup_k<<<SETUP_GRID, 256, 0, stream>>>(ei, batch, w1, w2, w3,
                                            b1, g1, be1, m1, v1,
                                            b2, g2, be2, m2, v2,
                                            b3, g3, be3, m3, v3,
                                            btg, bnsc, bnsh, cursor, psum, gcnt,
                                            flags);
    passA_k<<<PASSA_WG, 256, 0, stream>>>(ei, flags, cursor, pairs);
    passB_k<<<NBK, 256, 0, stream>>>(pairs, cursor, offs, degcnt, dinv, csr);

    const int ggrid = (NN + 63) / 64;          // 1563 (covers row NN sentinel too)
    const int fgrid = NN / 16;                 // 6250 (exact)

    // L1: x @ W1 -> bufA (dinv-scaled fp8 gather table)
    gemm_mfma_k<<<ggrid, 256, 0, stream>>>(x_in, btg, dinv, bufA, NN);
    // L1 aggregate + BN1 + ReLU fused with W2 gemm -> bufB (fp8)
    agg_gemm_k<<<fgrid, 256, 0, stream>>>(bufA, csr, offs, degcnt, dinv,
                                          bnsc, bnsh, btg + 8192, bufB);
    // L2 aggregate + BN2 + ReLU fused with W3 gemm -> bufA (fp8)
    agg_gemm_k<<<fgrid, 256, 0, stream>>>(bufB, csr, offs, degcnt, dinv,
                                          bnsc + 128, bnsh + 128, btg + 16384, bufA);
    // L3 aggregate + BN3 + ReLU + mean-pool partials
    agg_pool_k<<<fgrid, 256, 0, stream>>>(bufA, csr, offs, degcnt, dinv,
                                          bnsc + 256, bnsh + 256, batch, flags,
                                          psum, gcnt);
    head_k<<<GG, 128, 0, stream>>>(psum, gcnt, fw1, fb1, fw2, fb2, out);
}